// Round 1
// baseline (2490.606 us; speedup 1.0000x reference)
//
#include <hip/hip_runtime.h>

#define T_STRIDE 8192
#define CRES 64
#define CSKIP 128
#define SKIPN 4096
#define NB 8
#define TT 64
#define N_LAYERS 40

// ---------------------------------------------------------------------------
// Repack weights k-major so per-k weight rows are contiguous (scalar-load
// friendly):
//   wcatT [L][128][64]: wcatT[l][k][o] = k<64 ? w_dil[l][o][k][0] : w_dil[l][o][k-64][1]
//   wresT [L][64][64] : wresT[l][k][o] = w_res[l][o][k]
//   wskipT[L][64][128]: wskipT[l][k][o2] = w_skip[l][o2][k]
// ---------------------------------------------------------------------------
#define N_WCAT (N_LAYERS * 128 * 64)
#define N_WRES (N_LAYERS * 64 * 64)
#define N_WSKIP (N_LAYERS * 64 * 128)

__global__ void repack_kernel(const float* __restrict__ wdil,
                              const float* __restrict__ wres,
                              const float* __restrict__ wskip,
                              float* __restrict__ wcatT,
                              float* __restrict__ wresT,
                              float* __restrict__ wskipT) {
    int idx = blockIdx.x * 256 + threadIdx.x;
    if (idx < N_WCAT) {
        int o = idx & 63;
        int k = (idx >> 6) & 127;
        int l = idx >> 13;
        float v = (k < 64) ? wdil[((l * 64 + o) * 64 + k) * 2]
                           : wdil[((l * 64 + o) * 64 + (k - 64)) * 2 + 1];
        wcatT[idx] = v;
    } else if (idx < N_WCAT + N_WRES) {
        int j = idx - N_WCAT;
        int o = j & 63;
        int k = (j >> 6) & 63;
        int l = j >> 12;
        wresT[j] = wres[(l * 64 + o) * 64 + k];
    } else if (idx < N_WCAT + N_WRES + N_WSKIP) {
        int j = idx - N_WCAT - N_WRES;
        int o = j & 127;
        int k = (j >> 7) & 63;
        int l = j >> 13;
        wskipT[j] = wskip[(l * 128 + o) * 64 + k];
    }
}

// ---------------------------------------------------------------------------
// One residual-stack layer, fused: dilated conv -> tanh*sigmoid gate ->
// (res 1x1 + residual add) and (skip 1x1, last 4096 t).
// Stream layout: [b][c][t] fp32, t-stride fixed at 8192.
// Block: 256 threads = 4 waves. TT=64 timesteps/block; wave w owns output
// channels [16w,16w+16) (and skip channels [32w,32w+32)); lane = column t.
// ---------------------------------------------------------------------------
__global__ __launch_bounds__(256)
void layer_kernel(const float* __restrict__ in, float* __restrict__ outn,
                  const float* __restrict__ wcatT,   // [128][64]
                  const float* __restrict__ wresT,   // [64][64]
                  const float* __restrict__ bres,    // [64]
                  const float* __restrict__ wskipT,  // [64][128]
                  const float* __restrict__ bskip,   // [128]
                  float* __restrict__ skipout,       // [B][128][4096]
                  int d, int Lp, int skip_start) {
    __shared__ float Xc[128][TT];   // rows 0..63: in[c][t'], rows 64..127: in[c][t'+d]
    __shared__ float G[64][TT];     // gated activations

    const int tid = threadIdx.x;
    const int lane = tid & 63;
    const int w = tid >> 6;
    const int wu = __builtin_amdgcn_readfirstlane(w);  // wave-uniform -> s_loads
    const int b = blockIdx.y;
    const int t0 = blockIdx.x * TT;
    const int tp = t0 + lane;            // output timestep t'
    const int tcl = min(tp, Lp - 1);     // clamped for OOB lanes of last tile

    // ---- stage both dilation taps into LDS (coalesced along t) ----
    const float* inb = in + (size_t)b * CRES * T_STRIDE;
    #pragma unroll
    for (int r = 0; r < 32; r++) {
        int row = w + r * 4;                       // rows 0..127
        int c = row & 63;
        int tt = (row < 64) ? tcl : tcl + d;       // tcl+d <= L-1: in-bounds
        Xc[row][lane] = inb[c * T_STRIDE + tt];
    }
    __syncthreads();

    // ---- dilated conv: y[o] = sum_k wcatT[k][o] * Xc[k][lane] ----
    float acc[16];
    #pragma unroll
    for (int o = 0; o < 16; o++) acc[o] = 0.0f;
    #pragma unroll 4
    for (int k = 0; k < 128; k++) {
        float x = Xc[k][lane];
        const float* wk = wcatT + k * 64 + wu * 16;   // uniform -> s_load_dwordx8
        #pragma unroll
        for (int o = 0; o < 16; o++) acc[o] = fmaf(wk[o], x, acc[o]);
    }

    // ---- gate: tanh(y)*sigmoid(y) = (1-e^-y)/(1+e^-2y) ----
    #pragma unroll
    for (int o = 0; o < 16; o++) {
        float y = acc[o];
        float t = __expf(-y);
        float g = (1.0f - t) / fmaf(t, t, 1.0f);
        G[wu * 16 + o][lane] = g;
    }
    __syncthreads();

    // ---- res 1x1 + bias + residual add ----
    float r2[16];
    #pragma unroll
    for (int o = 0; o < 16; o++) r2[o] = bres[wu * 16 + o];
    #pragma unroll 4
    for (int k = 0; k < 64; k++) {
        float g = G[k][lane];
        const float* wk = wresT + k * 64 + wu * 16;
        #pragma unroll
        for (int o = 0; o < 16; o++) r2[o] = fmaf(wk[o], g, r2[o]);
    }
    if (tp < Lp) {
        float* ob = outn + (size_t)b * CRES * T_STRIDE;
        #pragma unroll
        for (int o = 0; o < 16; o++) {
            int c = wu * 16 + o;
            ob[c * T_STRIDE + tp] = r2[o] + Xc[64 + c][lane];  // + out[c][t'+d]
        }
    }

    // ---- skip 1x1 (only if this tile intersects the last-4096 window) ----
    if (t0 + TT - 1 >= skip_start) {
        float r3[32];
        #pragma unroll
        for (int j = 0; j < 32; j++) r3[j] = bskip[wu * 32 + j];
        #pragma unroll 4
        for (int k = 0; k < 64; k++) {
            float g = G[k][lane];
            const float* wk = wskipT + k * 128 + wu * 32;
            #pragma unroll
            for (int j = 0; j < 32; j++) r3[j] = fmaf(wk[j], g, r3[j]);
        }
        if (tp >= skip_start && tp < Lp) {
            float* sb = skipout + (size_t)b * CSKIP * SKIPN + (tp - skip_start);
            #pragma unroll
            for (int j = 0; j < 32; j++) sb[(size_t)(wu * 32 + j) * SKIPN] = r3[j];
        }
    }
}

// ---------------------------------------------------------------------------
// Host: repack weights once, then 40 stream-ordered layer launches with
// ping-pong stream buffers in d_ws.
// ws layout: bufA @0 (16MiB) | bufB @16MiB | wcatT @32MiB | wresT | wskipT
// total ~35.4MB.
// ---------------------------------------------------------------------------
extern "C" void kernel_launch(void* const* d_in, const int* in_sizes, int n_in,
                              void* d_out, int out_size, void* d_ws, size_t ws_size,
                              hipStream_t stream) {
    const float* x = (const float*)d_in[0];
    const float* wdil = (const float*)d_in[1];
    const float* wres = (const float*)d_in[2];
    const float* bres = (const float*)d_in[3];
    const float* wskip = (const float*)d_in[4];
    const float* bskip = (const float*)d_in[5];
    float* out = (float*)d_out;

    char* ws = (char*)d_ws;
    const size_t STREAM_BYTES = (size_t)NB * CRES * T_STRIDE * sizeof(float);  // 16 MiB
    float* bufA = (float*)ws;
    float* bufB = (float*)(ws + STREAM_BYTES);
    float* wcatT = (float*)(ws + 2 * STREAM_BYTES);
    float* wresT = wcatT + N_WCAT;
    float* wskipT = wresT + N_WRES;

    {
        int total = N_WCAT + N_WRES + N_WSKIP;
        int blocks = (total + 255) / 256;
        repack_kernel<<<blocks, 256, 0, stream>>>(wdil, wres, wskip, wcatT, wresT, wskipT);
    }

    int L = T_STRIDE;
    const float* cur = x;
    float* nxt = bufA;
    for (int i = 0; i < N_LAYERS; i++) {
        int d = 1 << (i % 10);
        int Lp = L - d;
        dim3 grid((Lp + TT - 1) / TT, NB);
        layer_kernel<<<grid, 256, 0, stream>>>(
            cur, nxt,
            wcatT + (size_t)i * 128 * 64,
            wresT + (size_t)i * 64 * 64,
            bres + (size_t)i * 64,
            wskipT + (size_t)i * 64 * 128,
            bskip + (size_t)i * 128,
            out + (size_t)i * NB * CSKIP * SKIPN,
            d, Lp, Lp - SKIPN);
        cur = nxt;
        nxt = (nxt == bufA) ? bufB : bufA;
        L = Lp;
    }
}